// Round 15
// baseline (10096.030 us; speedup 1.0000x reference)
//
#include <hip/hip_runtime.h>
#include <cstdint>
#include <cstddef>

// ============================================================================
// PointerNet: encoder LSTM (B=512,S=256,D=2,H=256) + autoregressive pointer
// decode with jax.random.categorical (threefry2x32 partitionable, key 42).
// Output: int32 indices [512][256], trajectory-exact vs JAX reference.
//
// R19 = R18 - din LDS staging - barrier S3.
// R18 post-mortem: early argmax publish neutral (RT never exposed). The one
// remaining serial-latency window is the din GATHER: 256 uncoalesced 16B
// encK4 loads by 4 waves (~900cy HBM, ~32 outstanding => 1-3us) while 12
// waves park at S3. But the Wi sweep consumes din as 4 WAVE-UNIFORM values
// per kk -> load them directly from encK4 as broadcast loads INSIDE the
// sweep, pipelined under the weight stream with 8-wave MLP. Same bytes,
// same f32 bits, same FMA order -> bit-exact. S3 deleted (mask->attention
// ordering has S4+S5 between; encK4 is own-block-written, no cross-block
// visibility needed). Each Wi wave computes the 4 winners redundantly from
// oVs/eV2 (cheap). red[17]->[18] keeps LDS at 82944B (>80KB) so the proven
// 1-block/CU 64-VGPR context is preserved after dinV's 4KB removal.
// Decoder step: 4 barriers (S1 partials, S2 argmax-exchange, S4 red full,
// S5 h ready). Everything else verbatim R18/R13 (absmax 0 proven).
// ============================================================================

typedef float v4f __attribute__((ext_vector_type(4)));
typedef unsigned long long u64;

#define WS_HX_OFF     0u                 // [128 g][2 H][512] u64 = 1 MB
#define WS_AMX_OFF    (1u << 20)         // [128 g][2 H][8] u64 = 16 KB
#define WS_SYNC_BYTES 0x110000u
#define WS_ENCW4_OFF  (2u << 20)         // [256 k][256 u][4 g] f32
#define WS_DECWI4_OFF (3u << 20)
#define WS_DECWH4_OFF (4u << 20)
#define WS_ENCK4_OFF  (5u << 20)         // [512 b][64 u4][256 s][4] f32
#define WS_NEEDED     ((size_t)(5u << 20) + (size_t)512 * 64 * 256 * 16)

__device__ __forceinline__ unsigned rotl32(unsigned x, int r) {
  return (x << r) | (x >> (32 - r));
}
__device__ __forceinline__ float sigm(float x) { return 1.f / (1.f + expf(-x)); }

__device__ __forceinline__ u64 pk(unsigned tag, unsigned payload) {
  return ((u64)tag << 32) | (u64)payload;
}
// argmax partial: [tag9:24][val:32][idx:8]; tag = t+1 (1..256, never 0)
__device__ __forceinline__ u64 pk49(unsigned tag9, float v, int idx) {
  return ((u64)tag9 << 40) | ((u64)__float_as_uint(v) << 8) | (u64)(idx & 0xFF);
}
// device-scope atomic read (resolves at coherence point; no stale L1/L2)
__device__ __forceinline__ unsigned spinrd(u64* p, unsigned tag) {
  u64 v = atomicAdd(p, 0ull);
  while ((unsigned)(v >> 32) != tag) {
    __builtin_amdgcn_s_sleep(2);
    v = atomicAdd(p, 0ull);
  }
  return (unsigned)v;
}
__device__ __forceinline__ u64 spinrd49(u64* p, unsigned tag9) {
  u64 v = atomicAdd(p, 0ull);
  while ((unsigned)(v >> 40) != tag9) {
    __builtin_amdgcn_s_sleep(2);
    v = atomicAdd(p, 0ull);
  }
  return v;
}

// Threefry-2x32, 20 rounds (jax._src.prng schedule) — verified exact R1-R18.
__device__ __forceinline__ void tf2(unsigned k0, unsigned k1,
                                    unsigned& x0, unsigned& x1) {
  const unsigned k2 = k0 ^ k1 ^ 0x1BD11BDAu;
  x0 += k0; x1 += k1;
  x0 += x1; x1 = rotl32(x1, 13); x1 ^= x0;
  x0 += x1; x1 = rotl32(x1, 15); x1 ^= x0;
  x0 += x1; x1 = rotl32(x1, 26); x1 ^= x0;
  x0 += x1; x1 = rotl32(x1,  6); x1 ^= x0;
  x0 += k1; x1 += k2 + 1u;
  x0 += x1; x1 = rotl32(x1, 17); x1 ^= x0;
  x0 += x1; x1 = rotl32(x1, 29); x1 ^= x0;
  x0 += x1; x1 = rotl32(x1, 16); x1 ^= x0;
  x0 += x1; x1 = rotl32(x1, 24); x1 ^= x0;
  x0 += k2; x1 += k0 + 2u;
  x0 += x1; x1 = rotl32(x1, 13); x1 ^= x0;
  x0 += x1; x1 = rotl32(x1, 15); x1 ^= x0;
  x0 += x1; x1 = rotl32(x1, 26); x1 ^= x0;
  x0 += x1; x1 = rotl32(x1,  6); x1 ^= x0;
  x0 += k0; x1 += k1 + 3u;
  x0 += x1; x1 = rotl32(x1, 17); x1 ^= x0;
  x0 += x1; x1 = rotl32(x1, 29); x1 ^= x0;
  x0 += x1; x1 = rotl32(x1, 16); x1 ^= x0;
  x0 += x1; x1 = rotl32(x1, 24); x1 ^= x0;
  x0 += k1; x1 += k2 + 4u;
  x0 += x1; x1 = rotl32(x1, 13); x1 ^= x0;
  x0 += x1; x1 = rotl32(x1, 15); x1 ^= x0;
  x0 += x1; x1 = rotl32(x1, 26); x1 ^= x0;
  x0 += x1; x1 = rotl32(x1,  6); x1 ^= x0;
  x0 += k2; x1 += k0 + 5u;
}

// Repack W [1024 rows][256 k] row-major -> [k][u][gate] (float4 per (k,u)).
__global__ void repack_k(const float* __restrict__ eWh,
                         const float* __restrict__ dWi,
                         const float* __restrict__ dWh,
                         float* __restrict__ ws) {
  float* encW4 = (float*)((char*)ws + WS_ENCW4_OFF);
  float* decWi4 = (float*)((char*)ws + WS_DECWI4_OFF);
  float* decWh4 = (float*)((char*)ws + WS_DECWH4_OFF);
  const int n = blockIdx.x * blockDim.x + threadIdx.x;   // 65536 = 256k x 256u
  if (n >= 65536) return;
  const int k = n >> 8, u = n & 255;
#pragma unroll
  for (int g = 0; g < 4; ++g) {
    const int src = ((g << 8) + u) * 256 + k;
    const int dst = (n << 2) + g;
    encW4[dst] = eWh[src];
    decWi4[dst] = dWi[src];
    decWh4[dst] = dWh[src];
  }
}

__global__ void __launch_bounds__(1024)
ptrnet_kernel(const float* __restrict__ inp,    // [512][256][2]
              const float* __restrict__ eWi,    // [1024][2]
              const float* __restrict__ eBi, const float* __restrict__ eBh,
              const float* __restrict__ dBi, const float* __restrict__ dBh,
              int* __restrict__ out,            // [512][256]
              float* __restrict__ ws) {
  const int tid  = threadIdx.x;
  const int wave = tid >> 6, l = tid & 63;
  const int kq   = wave >> 2;               // encoder/prologue partition
  const int uw   = wave & 3;
  const int uP   = (uw << 6) | l;
  const int k4b  = kq << 4;
  const int bA   = tid >> 8;                // encoder P2 partition
  const int uA   = tid & 255;

  const int g    = blockIdx.x & 127;        // pair id
  const int H    = blockIdx.x >> 7;         // half: 0 = lo, 1 = hi
  const int b0   = g << 2;
  const int bG   = b0 + bA;
  const int ubase = H << 7;                 // owned u range [ubase, ubase+128)
  const int pbase = ubase ^ 128;            // partner's u base
  const int sbase = H << 7;                 // owned s range

  const v4f* encW4  = (const v4f*)((char*)ws + WS_ENCW4_OFF);
  const v4f* decWi4 = (const v4f*)((char*)ws + WS_DECWI4_OFF);
  const v4f* decWh4 = (const v4f*)((char*)ws + WS_DECWH4_OFF);
  v4f* encK4 = (v4f*)((char*)ws + WS_ENCK4_OFF);

  u64* hxAll  = (u64*)((char*)ws + WS_HX_OFF);
  u64* hxMe   = hxAll + (size_t)g * 1024 + (size_t)H * 512;
  u64* hxYo   = hxAll + (size_t)g * 1024 + (size_t)(1 - H) * 512;
  u64* amxAll = (u64*)((char*)ws + WS_AMX_OFF);
  u64* amxMe  = amxAll + (size_t)g * 16 + (size_t)H * 8;
  u64* amxYo  = amxAll + (size_t)g * 16 + (size_t)(1 - H) * 8;

  __shared__ __align__(16) float hsF[2][1024];   // h dbuf: [buf][b*256+u]
  // red[18]: rows 0-15 partials, rows 16-17 pad -> LDS stays 82944B (>80KB)
  // so the proven 1-block/CU 64-VGPR compiler context is preserved.
  __shared__ __align__(16) v4f red[18][256];
  __shared__ unsigned char maskC[4][128];        // own s-half mask
  __shared__ float partV[4][2];
  __shared__ int   partI[4][2];
  __shared__ float oVs[4]; __shared__ int oIs[4];   // own half combined
  __shared__ float eV2[4][2]; __shared__ int eI2[4][2];  // partner wave partials

  // ---- encoder activation constants (keyed by uA) ----
  const float ebi_ = eBi[uA] + eBh[uA];
  const float ebf_ = eBi[256 + uA] + eBh[256 + uA];
  const float ebg_ = eBi[512 + uA] + eBh[512 + uA];
  const float ebo_ = eBi[768 + uA] + eBh[768 + uA];
  const float wxi0 = eWi[2 * uA], wxi1 = eWi[2 * uA + 1];
  const float wxf0 = eWi[2 * (256 + uA)], wxf1 = eWi[2 * (256 + uA) + 1];
  const float wxg0 = eWi[2 * (512 + uA)], wxg1 = eWi[2 * (512 + uA) + 1];
  const float wxo0 = eWi[2 * (768 + uA)], wxo1 = eWi[2 * (768 + uA) + 1];

  hsF[0][tid] = 0.f;
  __syncthreads();

  float c = 0.f;
  int p = 0;

  // ---------------- encoder: 256 steps (R10-exact, redundant per pair) ------
  for (int t = 0; t < 256; ++t) {
    v4f a0 = (v4f)0.f, a1 = (v4f)0.f, a2 = (v4f)0.f, a3 = (v4f)0.f;
    const v4f* Wp = encW4 + uP;
    const v4f* hq = (const v4f*)&hsF[p][0];
#pragma unroll 2
    for (int kk = 0; kk < 16; ++kk) {
      const int k4 = k4b + kk;
      const v4f w0 = Wp[(k4 * 4 + 0) << 8];
      const v4f w1 = Wp[(k4 * 4 + 1) << 8];
      const v4f w2 = Wp[(k4 * 4 + 2) << 8];
      const v4f w3 = Wp[(k4 * 4 + 3) << 8];
      const v4f h0 = hq[k4];
      const v4f h1 = hq[64 + k4];
      const v4f h2 = hq[128 + k4];
      const v4f h3 = hq[192 + k4];
      a0 += w0 * h0.x + w1 * h0.y + w2 * h0.z + w3 * h0.w;
      a1 += w0 * h1.x + w1 * h1.y + w2 * h1.z + w3 * h1.w;
      a2 += w0 * h2.x + w1 * h2.y + w2 * h2.z + w3 * h2.w;
      a3 += w0 * h3.x + w1 * h3.y + w2 * h3.z + w3 * h3.w;
    }
    red[(kq << 2) | 0][uP] = a0;
    red[(kq << 2) | 1][uP] = a1;
    red[(kq << 2) | 2][uP] = a2;
    red[(kq << 2) | 3][uP] = a3;
    __syncthreads();
    const v4f gv = red[bA][uA] + red[4 + bA][uA] + red[8 + bA][uA] + red[12 + bA][uA];
    const float2 xv = *(const float2*)(inp + (((bG) << 8) + t) * 2);
    const float ai = gv.x + ebi_ + wxi0 * xv.x + wxi1 * xv.y;
    const float af = gv.y + ebf_ + wxf0 * xv.x + wxf1 * xv.y;
    const float ag = gv.z + ebg_ + wxg0 * xv.x + wxg1 * xv.y;
    const float ao = gv.w + ebo_ + wxo0 * xv.x + wxo1 * xv.y;
    const float iv = sigm(ai), fv = sigm(af), gva = tanhf(ag), ov = sigm(ao);
    c = fv * c + iv * gva;
    const float hn = ov * tanhf(c);
    hsF[p ^ 1][(bA << 8) | uA] = hn;
    ((float*)encK4)[(((bG << 6) + (uA >> 2)) << 10) + (t << 2) + (uA & 3)] = hn;
    __syncthreads();
    p ^= 1;
  }

  // ---------------- decoder setup: c handoff to split mapping ----------------
  float* creg = (float*)&red[0][0];
  creg[(bA << 8) | uA] = c;
  const int isP2 = tid < 512;
  const int bD = tid >> 7;                  // 0..3   (valid if isP2)
  const int uL = tid & 127;
  const int uD = ubase | uL;                // owned global u
  __syncthreads();
  float cD = 0.f, dbi2 = 0.f, dbf2 = 0.f, dbg2 = 0.f, dbo2 = 0.f;
  if (isP2) {
    cD = creg[(bD << 8) | uD];
    dbi2 = dBi[uD] + dBh[uD];
    dbf2 = dBi[256 + uD] + dBh[256 + uD];
    dbg2 = dBi[512 + uD] + dBh[512 + uD];
    dbo2 = dBi[768 + uD] + dBh[768 + uD];
  }
  // attn identity (valid for wave >= 8)
  const int aw  = wave - 8;
  const int bAt = aw >> 1;
  const int sL  = ((aw & 1) << 6) | l;
  const int sG  = sbase | sL;
  const int bGt = b0 + bAt;
  if (wave >= 8) maskC[bAt][sL] = 0;
  // Wh/Wi identity (valid for wave < 8)
  const int kqD  = wave >> 1;
  const int k4bD = kqD << 4;
  const int uPD  = ubase | ((wave & 1) << 6) | l;
  const float NEG_INF = __int_as_float((int)0xff800000);
  __syncthreads();                           // creg consumed; red free

  // ---- prologue: LSTM step 0 (din=0, Wi exact-0 skipped). Wh redundant
  //      16-wave full-u (identical values in both blocks); P2 split. ----
  {
    v4f a0 = (v4f)0.f, a1 = (v4f)0.f, a2 = (v4f)0.f, a3 = (v4f)0.f;
    const v4f* Wh = decWh4 + uP;
    const v4f* hq = (const v4f*)&hsF[p][0];
#pragma unroll 2
    for (int kk = 0; kk < 16; ++kk) {
      const int k4 = k4b + kk;
      const v4f w0 = Wh[(k4 * 4 + 0) << 8];
      const v4f w1 = Wh[(k4 * 4 + 1) << 8];
      const v4f w2 = Wh[(k4 * 4 + 2) << 8];
      const v4f w3 = Wh[(k4 * 4 + 3) << 8];
      const v4f h0 = hq[k4];
      const v4f h1 = hq[64 + k4];
      const v4f h2 = hq[128 + k4];
      const v4f h3 = hq[192 + k4];
      a0 += w0 * h0.x + w1 * h0.y + w2 * h0.z + w3 * h0.w;
      a1 += w0 * h1.x + w1 * h1.y + w2 * h1.z + w3 * h1.w;
      a2 += w0 * h2.x + w1 * h2.y + w2 * h2.z + w3 * h2.w;
      a3 += w0 * h3.x + w1 * h3.y + w2 * h3.z + w3 * h3.w;
    }
    red[(kq << 2) | 0][uP] = a0;
    red[(kq << 2) | 1][uP] = a1;
    red[(kq << 2) | 2][uP] = a2;
    red[(kq << 2) | 3][uP] = a3;
    __syncthreads();
    if (isP2) {
      const v4f gv = red[bD][uD] + red[4 + bD][uD] + red[8 + bD][uD] + red[12 + bD][uD];
      const float iv = sigm(gv.x + dbi2), fv = sigm(gv.y + dbf2);
      const float gva = tanhf(gv.z + dbg2), ov = sigm(gv.w + dbo2);
      cD = fv * cD + iv * gva;
      const float hn = ov * tanhf(cD);
      hsF[p ^ 1][(bD << 8) | uD] = hn;
      atomicExch(&hxMe[(bD << 7) | uL], pk(0xA5000000u, __float_as_uint(hn)));
      const unsigned pw = spinrd(&hxYo[(bD << 7) | uL], 0xA5000000u);
      hsF[p ^ 1][(bD << 8) | pbase | uL] = __uint_as_float(pw);
    }
    __syncthreads();
    p ^= 1;                                   // hsF[p] = full h_0
  }

  // winner fold: max val, min idx on ties — order-independent semantics
#define WINNER(B, WI) { float _wv = oVs[B]; int _wi = oIs[B];                 \
    { const float _e = eV2[B][0]; const int _i = eI2[B][0];                   \
      if (_e > _wv || (_e == _wv && _i < _wi)) { _wv = _e; _wi = _i; } }      \
    { const float _e = eV2[B][1]; const int _i = eI2[B][1];                   \
      if (_e > _wv || (_e == _wv && _i < _wi)) { _wv = _e; _wi = _i; } }      \
    WI = _wi; }

  for (int t = 0; t < 256; ++t) {
    const unsigned tagA9 = (unsigned)t + 1u;  // 1..256, never 0
    const unsigned tagH = 0xA5000002u + 2u * (unsigned)t;
    const v4f* hq = (const v4f*)&hsF[p][0];

    // ==== phase X: waves 0-7 Wh·h_t (u-half) ∥ waves 8-15 attention(t) ====
    if (wave < 8) {
      v4f a0 = (v4f)0.f, a1 = (v4f)0.f, a2 = (v4f)0.f, a3 = (v4f)0.f;
      const v4f* Wh = decWh4 + uPD;
#pragma unroll 2
      for (int kk = 0; kk < 16; ++kk) {
        const int k4 = k4bD + kk;
        const v4f w0 = Wh[(k4 * 4 + 0) << 8];
        const v4f w1 = Wh[(k4 * 4 + 1) << 8];
        const v4f w2 = Wh[(k4 * 4 + 2) << 8];
        const v4f w3 = Wh[(k4 * 4 + 3) << 8];
        const v4f h0 = hq[k4];
        const v4f h1 = hq[64 + k4];
        const v4f h2 = hq[128 + k4];
        const v4f h3 = hq[192 + k4];
        a0 += w0 * h0.x + w1 * h0.y + w2 * h0.z + w3 * h0.w;
        a1 += w0 * h1.x + w1 * h1.y + w2 * h1.z + w3 * h1.w;
        a2 += w0 * h2.x + w1 * h2.y + w2 * h2.z + w3 * h2.w;
        a3 += w0 * h3.x + w1 * h3.y + w2 * h3.z + w3 * h3.w;
      }
      red[(kqD << 2) | 0][uPD] = a0;
      red[(kqD << 2) | 1][uPD] = a1;
      red[(kqD << 2) | 2][uPD] = a2;
      red[(kqD << 2) | 3][uPD] = a3;
    } else {
      const int masked = maskC[bAt][sL];
      float sc = 0.f;
      if (!masked) {
        const v4f* E = encK4 + (bGt << 14) + sG;
        const v4f* hq2 = hq + (bAt << 6);
#pragma unroll 4
        for (int k4 = 0; k4 < 64; ++k4) {
          const v4f ev = E[k4 << 8];
          const v4f hv = hq2[k4];
          sc += ev.x * hv.x + ev.y * hv.y + ev.z * hv.z + ev.w * hv.w;
        }
      }
      unsigned bits;
      {
        unsigned kk0 = 0u, kk1 = (unsigned)t;
        tf2(0u, 42u, kk0, kk1);
        unsigned y0 = 0u, y1 = (unsigned)((bGt << 8) + sG);
        tf2(kk0, kk1, y0, y1);
        bits = y0 ^ y1;
      }
      const float fr = __uint_as_float((bits >> 9) | 0x3f800000u) - 1.0f;
      const float uu = (fr > 0.f) ? fr : 1.17549435e-38f;
      const float gum = -logf(-logf(uu));
      float bv = masked ? NEG_INF : (sc + gum);
      int bi = sG;
#pragma unroll
      for (int off = 32; off; off >>= 1) {
        const float ov2 = __shfl_xor(bv, off, 64);
        const int oi2 = __shfl_xor(bi, off, 64);
        if (ov2 > bv || (ov2 == bv && oi2 < bi)) { bv = ov2; bi = oi2; }
      }
      if (l == 0) {
        partV[bAt][aw & 1] = bv; partI[bAt][aw & 1] = bi;
        // EARLY publish: in flight while Wh waves finish their stream
        atomicExch(&amxMe[(bAt << 1) | (aw & 1)], pk49(tagA9, bv, bi));
      }
    }
    __syncthreads();                          // S1: red-Wh + partials ready

    // ==== own combine (tid 0-3); spin partner per-wave words (tid 64-71) ====
    if (tid < 4) {
      float v0 = partV[tid][0]; int i0 = partI[tid][0];
      const float v1 = partV[tid][1];
      if (v1 > v0) { v0 = v1; i0 = partI[tid][1]; }   // strict >: lower s kept
      oVs[tid] = v0; oIs[tid] = i0;
    }
    if (tid >= 64 && tid < 72) {
      const int j = tid - 64;                 // (batch<<1)|wv
      const u64 w = spinrd49(&amxYo[j], tagA9);
      eV2[j >> 1][j & 1] = __uint_as_float((unsigned)(w >> 8));
      eI2[j >> 1][j & 1] = (int)(w & 0xFF);
    }
    __syncthreads();                          // S2: both halves' results ready

    // ==== winner, mask, out (no din staging, no S3) ====
    if (wave >= 8) {
      int wi; WINNER(bAt, wi);
      if (sG == wi) maskC[bAt][sL] = 1;       // read next step after S5: ordered
    }
    if (H == 0 && tid < 4) {
      int wi; WINNER(tid, wi);
      out[((b0 + tid) << 8) + t] = wi;
    }

    if (t == 255) break;                      // last index emitted

    // ==== Wi·din sweep (waves 0-7): din loaded DIRECTLY from encK4 as
    //      wave-uniform broadcast loads, pipelined under the weight stream.
    //      Same bits as the staged dinV -> bit-exact chain from red. ====
    if (wave < 8) {
      int wn0, wn1, wn2, wn3;                 // winners, redundant per thread
      WINNER(0, wn0) WINNER(1, wn1) WINNER(2, wn2) WINNER(3, wn3)
      const v4f* E0 = encK4 + ((size_t)(b0 + 0) << 14) + wn0;
      const v4f* E1 = encK4 + ((size_t)(b0 + 1) << 14) + wn1;
      const v4f* E2 = encK4 + ((size_t)(b0 + 2) << 14) + wn2;
      const v4f* E3 = encK4 + ((size_t)(b0 + 3) << 14) + wn3;
      v4f a0 = red[(kqD << 2) | 0][uPD];
      v4f a1 = red[(kqD << 2) | 1][uPD];
      v4f a2 = red[(kqD << 2) | 2][uPD];
      v4f a3 = red[(kqD << 2) | 3][uPD];
      const v4f* Wi = decWi4 + uPD;
#pragma unroll 2
      for (int kk = 0; kk < 16; ++kk) {
        const int k4 = k4bD + kk;
        const v4f w0 = Wi[(k4 * 4 + 0) << 8];
        const v4f w1 = Wi[(k4 * 4 + 1) << 8];
        const v4f w2 = Wi[(k4 * 4 + 2) << 8];
        const v4f w3 = Wi[(k4 * 4 + 3) << 8];
        const v4f d0 = E0[k4 << 8];           // din[b][k4] = encK4[b][k4][win]
        const v4f d1 = E1[k4 << 8];
        const v4f d2 = E2[k4 << 8];
        const v4f d3 = E3[k4 << 8];
        a0 += w0 * d0.x + w1 * d0.y + w2 * d0.z + w3 * d0.w;
        a1 += w0 * d1.x + w1 * d1.y + w2 * d1.z + w3 * d1.w;
        a2 += w0 * d2.x + w1 * d2.y + w2 * d2.z + w3 * d2.w;
        a3 += w0 * d3.x + w1 * d3.y + w2 * d3.z + w3 * d3.w;
      }
      red[(kqD << 2) | 0][uPD] = a0;
      red[(kqD << 2) | 1][uPD] = a1;
      red[(kqD << 2) | 2][uPD] = a2;
      red[(kqD << 2) | 3][uPD] = a3;
    }
    __syncthreads();                          // S4: full partials ready

    // ==== P2 (split) -> h_{t+1}; publish + fetch partner half ====
    if (isP2) {
      const v4f gv = red[bD][uD] + red[4 + bD][uD] + red[8 + bD][uD] + red[12 + bD][uD];
      const float iv = sigm(gv.x + dbi2), fv = sigm(gv.y + dbf2);
      const float gva = tanhf(gv.z + dbg2), ov = sigm(gv.w + dbo2);
      cD = fv * cD + iv * gva;
      const float hn = ov * tanhf(cD);
      hsF[p ^ 1][(bD << 8) | uD] = hn;
      atomicExch(&hxMe[(bD << 7) | uL], pk(tagH, __float_as_uint(hn)));
      const unsigned pw = spinrd(&hxYo[(bD << 7) | uL], tagH);
      hsF[p ^ 1][(bD << 8) | pbase | uL] = __uint_as_float(pw);
    }
    __syncthreads();                          // S5: full h_{t+1} ready
    p ^= 1;
  }
#undef WINNER
}

extern "C" void kernel_launch(void* const* d_in, const int* in_sizes, int n_in,
                              void* d_out, int out_size, void* d_ws, size_t ws_size,
                              hipStream_t stream) {
  (void)in_sizes; (void)n_in; (void)out_size;
  if (ws_size < WS_NEEDED) return;   // need ~139 MB scratch

  const float* inp = (const float*)d_in[0];
  const float* eWi = (const float*)d_in[1];
  const float* eWh = (const float*)d_in[2];
  const float* eBi = (const float*)d_in[3];
  const float* eBh = (const float*)d_in[4];
  const float* dWi = (const float*)d_in[5];
  const float* dWh = (const float*)d_in[6];
  const float* dBi = (const float*)d_in[7];
  const float* dBh = (const float*)d_in[8];
  int* out = (int*)d_out;
  float* wsf = (float*)d_ws;

  // zero the sync region every launch: fresh tags, no ABA across graph replays
  hipMemsetAsync((char*)d_ws + WS_HX_OFF, 0, WS_SYNC_BYTES, stream);
  hipLaunchKernelGGL(repack_k, dim3(256), dim3(256), 0, stream, eWh, dWi, dWh, wsf);
  hipLaunchKernelGGL(ptrnet_kernel, dim3(256), dim3(1024), 0, stream,
                     inp, eWi, eBi, eBh, dBi, dBh, out, wsf);
}

// Round 16
// 9254.326 us; speedup vs baseline: 1.0910x; 1.0910x over previous
//
#include <hip/hip_runtime.h>
#include <cstdint>
#include <cstddef>

// ============================================================================
// PointerNet: encoder LSTM (B=512,S=256,D=2,H=256) + autoregressive pointer
// decode with jax.random.categorical (threefry2x32 partitionable, key 42).
// Output: int32 indices [512][256], trajectory-exact vs JAX reference.
//
// R20 = R13 verbatim (best verified: 9294us, absmax 0) — final revert.
// R14-R19 falsified every remaining micro-theory one at a time:
//   R14/R15 encoder gate-split (either sync form): neutral/worse
//   R16 deeper load unrolls: worse       R17 Wi 16-wave split: bank conflicts
//   R18 early argmax publish: neutral    R19 din direct-load: worse
// Remaining decoder step (~12.5us) = split weight stream (~7.4us, per-CU L2
// share — proven by R13's halving) + serial h-exchange RT + 5 barrier drains
// of a cross-CU-coupled recurrence. This structure is at its measured floor.
//
// Structure: 256 blocks; pair (g, g+128) on same 4 batches; decoder u-split
// (weights/CU halved), s-split attention; tagged-u64 atomic exchange (argmax
// + h) — no fences, L2 weight cache untouched; encoder redundant per pair
// (R10-exact); 1 block/CU co-residency (LDS 82944B > 80KB).
// ============================================================================

typedef float v4f __attribute__((ext_vector_type(4)));
typedef unsigned long long u64;

#define WS_HX_OFF     0u                 // [128 g][2 H][512] u64 = 1 MB
#define WS_AMX_OFF    (1u << 20)         // [128 g][2 H][8] u64 = 16 KB
#define WS_SYNC_BYTES 0x110000u
#define WS_ENCW4_OFF  (2u << 20)         // [256 k][256 u][4 g] f32
#define WS_DECWI4_OFF (3u << 20)
#define WS_DECWH4_OFF (4u << 20)
#define WS_ENCK4_OFF  (5u << 20)         // [512 b][64 u4][256 s][4] f32
#define WS_NEEDED     ((size_t)(5u << 20) + (size_t)512 * 64 * 256 * 16)

__device__ __forceinline__ unsigned rotl32(unsigned x, int r) {
  return (x << r) | (x >> (32 - r));
}
__device__ __forceinline__ float sigm(float x) { return 1.f / (1.f + expf(-x)); }

__device__ __forceinline__ u64 pk(unsigned tag, unsigned payload) {
  return ((u64)tag << 32) | (u64)payload;
}
// device-scope atomic read (resolves at coherence point; no stale L1/L2)
__device__ __forceinline__ unsigned spinrd(u64* p, unsigned tag) {
  u64 v = atomicAdd(p, 0ull);
  while ((unsigned)(v >> 32) != tag) {
    __builtin_amdgcn_s_sleep(2);
    v = atomicAdd(p, 0ull);
  }
  return (unsigned)v;
}

// Threefry-2x32, 20 rounds (jax._src.prng schedule) — verified exact R1-R19.
__device__ __forceinline__ void tf2(unsigned k0, unsigned k1,
                                    unsigned& x0, unsigned& x1) {
  const unsigned k2 = k0 ^ k1 ^ 0x1BD11BDAu;
  x0 += k0; x1 += k1;
  x0 += x1; x1 = rotl32(x1, 13); x1 ^= x0;
  x0 += x1; x1 = rotl32(x1, 15); x1 ^= x0;
  x0 += x1; x1 = rotl32(x1, 26); x1 ^= x0;
  x0 += x1; x1 = rotl32(x1,  6); x1 ^= x0;
  x0 += k1; x1 += k2 + 1u;
  x0 += x1; x1 = rotl32(x1, 17); x1 ^= x0;
  x0 += x1; x1 = rotl32(x1, 29); x1 ^= x0;
  x0 += x1; x1 = rotl32(x1, 16); x1 ^= x0;
  x0 += x1; x1 = rotl32(x1, 24); x1 ^= x0;
  x0 += k2; x1 += k0 + 2u;
  x0 += x1; x1 = rotl32(x1, 13); x1 ^= x0;
  x0 += x1; x1 = rotl32(x1, 15); x1 ^= x0;
  x0 += x1; x1 = rotl32(x1, 26); x1 ^= x0;
  x0 += x1; x1 = rotl32(x1,  6); x1 ^= x0;
  x0 += k0; x1 += k1 + 3u;
  x0 += x1; x1 = rotl32(x1, 17); x1 ^= x0;
  x0 += x1; x1 = rotl32(x1, 29); x1 ^= x0;
  x0 += x1; x1 = rotl32(x1, 16); x1 ^= x0;
  x0 += x1; x1 = rotl32(x1, 24); x1 ^= x0;
  x0 += k1; x1 += k2 + 4u;
  x0 += x1; x1 = rotl32(x1, 13); x1 ^= x0;
  x0 += x1; x1 = rotl32(x1, 15); x1 ^= x0;
  x0 += x1; x1 = rotl32(x1, 26); x1 ^= x0;
  x0 += x1; x1 = rotl32(x1,  6); x1 ^= x0;
  x0 += k2; x1 += k0 + 5u;
}

// Repack W [1024 rows][256 k] row-major -> [k][u][gate] (float4 per (k,u)).
__global__ void repack_k(const float* __restrict__ eWh,
                         const float* __restrict__ dWi,
                         const float* __restrict__ dWh,
                         float* __restrict__ ws) {
  float* encW4 = (float*)((char*)ws + WS_ENCW4_OFF);
  float* decWi4 = (float*)((char*)ws + WS_DECWI4_OFF);
  float* decWh4 = (float*)((char*)ws + WS_DECWH4_OFF);
  const int n = blockIdx.x * blockDim.x + threadIdx.x;   // 65536 = 256k x 256u
  if (n >= 65536) return;
  const int k = n >> 8, u = n & 255;
#pragma unroll
  for (int g = 0; g < 4; ++g) {
    const int src = ((g << 8) + u) * 256 + k;
    const int dst = (n << 2) + g;
    encW4[dst] = eWh[src];
    decWi4[dst] = dWi[src];
    decWh4[dst] = dWh[src];
  }
}

__global__ void __launch_bounds__(1024)
ptrnet_kernel(const float* __restrict__ inp,    // [512][256][2]
              const float* __restrict__ eWi,    // [1024][2]
              const float* __restrict__ eBi, const float* __restrict__ eBh,
              const float* __restrict__ dBi, const float* __restrict__ dBh,
              int* __restrict__ out,            // [512][256]
              float* __restrict__ ws) {
  const int tid  = threadIdx.x;
  const int wave = tid >> 6, l = tid & 63;
  const int kq   = wave >> 2;               // encoder/prologue partition
  const int uw   = wave & 3;
  const int uP   = (uw << 6) | l;
  const int k4b  = kq << 4;
  const int bA   = tid >> 8;                // encoder P2 partition
  const int uA   = tid & 255;

  const int g    = blockIdx.x & 127;        // pair id
  const int H    = blockIdx.x >> 7;         // half: 0 = lo, 1 = hi
  const int b0   = g << 2;
  const int bG   = b0 + bA;
  const int ubase = H << 7;                 // owned u range [ubase, ubase+128)
  const int pbase = ubase ^ 128;            // partner's u base
  const int sbase = H << 7;                 // owned s range

  const v4f* encW4  = (const v4f*)((char*)ws + WS_ENCW4_OFF);
  const v4f* decWi4 = (const v4f*)((char*)ws + WS_DECWI4_OFF);
  const v4f* decWh4 = (const v4f*)((char*)ws + WS_DECWH4_OFF);
  v4f* encK4 = (v4f*)((char*)ws + WS_ENCK4_OFF);

  u64* hxAll  = (u64*)((char*)ws + WS_HX_OFF);
  u64* hxMe   = hxAll + (size_t)g * 1024 + (size_t)H * 512;
  u64* hxYo   = hxAll + (size_t)g * 1024 + (size_t)(1 - H) * 512;
  u64* amxAll = (u64*)((char*)ws + WS_AMX_OFF);
  u64* amxMe  = amxAll + (size_t)g * 16 + (size_t)H * 8;
  u64* amxYo  = amxAll + (size_t)g * 16 + (size_t)(1 - H) * 8;

  __shared__ __align__(16) float hsF[2][1024];   // h dbuf: [buf][b*256+u]
  __shared__ __align__(16) v4f dinV[256];        // dec_in [b][64 k4]
  __shared__ __align__(16) v4f red[17][256];     // partials; row 16 = LDS pad
  __shared__ unsigned char maskC[4][128];        // own s-half mask
  __shared__ float partV[4][2];
  __shared__ int   partI[4][2];
  __shared__ float oVs[4]; __shared__ int oIs[4];   // own half combined
  __shared__ float eVs[4]; __shared__ int eIs[4];   // partner half

  // ---- encoder activation constants (keyed by uA) ----
  const float ebi_ = eBi[uA] + eBh[uA];
  const float ebf_ = eBi[256 + uA] + eBh[256 + uA];
  const float ebg_ = eBi[512 + uA] + eBh[512 + uA];
  const float ebo_ = eBi[768 + uA] + eBh[768 + uA];
  const float wxi0 = eWi[2 * uA], wxi1 = eWi[2 * uA + 1];
  const float wxf0 = eWi[2 * (256 + uA)], wxf1 = eWi[2 * (256 + uA) + 1];
  const float wxg0 = eWi[2 * (512 + uA)], wxg1 = eWi[2 * (512 + uA) + 1];
  const float wxo0 = eWi[2 * (768 + uA)], wxo1 = eWi[2 * (768 + uA) + 1];

  hsF[0][tid] = 0.f;
  __syncthreads();

  float c = 0.f;
  int p = 0;

  // ---------------- encoder: 256 steps (R10-exact, redundant per pair) ------
  for (int t = 0; t < 256; ++t) {
    v4f a0 = (v4f)0.f, a1 = (v4f)0.f, a2 = (v4f)0.f, a3 = (v4f)0.f;
    const v4f* Wp = encW4 + uP;
    const v4f* hq = (const v4f*)&hsF[p][0];
#pragma unroll 2
    for (int kk = 0; kk < 16; ++kk) {
      const int k4 = k4b + kk;
      const v4f w0 = Wp[(k4 * 4 + 0) << 8];
      const v4f w1 = Wp[(k4 * 4 + 1) << 8];
      const v4f w2 = Wp[(k4 * 4 + 2) << 8];
      const v4f w3 = Wp[(k4 * 4 + 3) << 8];
      const v4f h0 = hq[k4];
      const v4f h1 = hq[64 + k4];
      const v4f h2 = hq[128 + k4];
      const v4f h3 = hq[192 + k4];
      a0 += w0 * h0.x + w1 * h0.y + w2 * h0.z + w3 * h0.w;
      a1 += w0 * h1.x + w1 * h1.y + w2 * h1.z + w3 * h1.w;
      a2 += w0 * h2.x + w1 * h2.y + w2 * h2.z + w3 * h2.w;
      a3 += w0 * h3.x + w1 * h3.y + w2 * h3.z + w3 * h3.w;
    }
    red[(kq << 2) | 0][uP] = a0;
    red[(kq << 2) | 1][uP] = a1;
    red[(kq << 2) | 2][uP] = a2;
    red[(kq << 2) | 3][uP] = a3;
    __syncthreads();
    const v4f gv = red[bA][uA] + red[4 + bA][uA] + red[8 + bA][uA] + red[12 + bA][uA];
    const float2 xv = *(const float2*)(inp + (((bG) << 8) + t) * 2);
    const float ai = gv.x + ebi_ + wxi0 * xv.x + wxi1 * xv.y;
    const float af = gv.y + ebf_ + wxf0 * xv.x + wxf1 * xv.y;
    const float ag = gv.z + ebg_ + wxg0 * xv.x + wxg1 * xv.y;
    const float ao = gv.w + ebo_ + wxo0 * xv.x + wxo1 * xv.y;
    const float iv = sigm(ai), fv = sigm(af), gva = tanhf(ag), ov = sigm(ao);
    c = fv * c + iv * gva;
    const float hn = ov * tanhf(c);
    hsF[p ^ 1][(bA << 8) | uA] = hn;
    ((float*)encK4)[(((bG << 6) + (uA >> 2)) << 10) + (t << 2) + (uA & 3)] = hn;
    __syncthreads();
    p ^= 1;
  }

  // ---------------- decoder setup: c handoff to split mapping ----------------
  float* creg = (float*)&red[0][0];
  creg[(bA << 8) | uA] = c;
  const int isP2 = tid < 512;
  const int bD = tid >> 7;                  // 0..3   (valid if isP2)
  const int uL = tid & 127;
  const int uD = ubase | uL;                // owned global u
  __syncthreads();
  float cD = 0.f, dbi2 = 0.f, dbf2 = 0.f, dbg2 = 0.f, dbo2 = 0.f;
  if (isP2) {
    cD = creg[(bD << 8) | uD];
    dbi2 = dBi[uD] + dBh[uD];
    dbf2 = dBi[256 + uD] + dBh[256 + uD];
    dbg2 = dBi[512 + uD] + dBh[512 + uD];
    dbo2 = dBi[768 + uD] + dBh[768 + uD];
  }
  // attn identity (valid for wave >= 8)
  const int aw  = wave - 8;
  const int bAt = aw >> 1;
  const int sL  = ((aw & 1) << 6) | l;
  const int sG  = sbase | sL;
  const int bGt = b0 + bAt;
  if (wave >= 8) maskC[bAt][sL] = 0;
  // Wh/Wi identity (valid for wave < 8)
  const int kqD  = wave >> 1;
  const int k4bD = kqD << 4;
  const int uPD  = ubase | ((wave & 1) << 6) | l;
  const float NEG_INF = __int_as_float((int)0xff800000);
  __syncthreads();                           // creg consumed; red free

  // ---- prologue: LSTM step 0 (din=0, Wi exact-0 skipped). Wh redundant
  //      16-wave full-u (identical values in both blocks); P2 split. ----
  {
    v4f a0 = (v4f)0.f, a1 = (v4f)0.f, a2 = (v4f)0.f, a3 = (v4f)0.f;
    const v4f* Wh = decWh4 + uP;
    const v4f* hq = (const v4f*)&hsF[p][0];
#pragma unroll 2
    for (int kk = 0; kk < 16; ++kk) {
      const int k4 = k4b + kk;
      const v4f w0 = Wh[(k4 * 4 + 0) << 8];
      const v4f w1 = Wh[(k4 * 4 + 1) << 8];
      const v4f w2 = Wh[(k4 * 4 + 2) << 8];
      const v4f w3 = Wh[(k4 * 4 + 3) << 8];
      const v4f h0 = hq[k4];
      const v4f h1 = hq[64 + k4];
      const v4f h2 = hq[128 + k4];
      const v4f h3 = hq[192 + k4];
      a0 += w0 * h0.x + w1 * h0.y + w2 * h0.z + w3 * h0.w;
      a1 += w0 * h1.x + w1 * h1.y + w2 * h1.z + w3 * h1.w;
      a2 += w0 * h2.x + w1 * h2.y + w2 * h2.z + w3 * h2.w;
      a3 += w0 * h3.x + w1 * h3.y + w2 * h3.z + w3 * h3.w;
    }
    red[(kq << 2) | 0][uP] = a0;
    red[(kq << 2) | 1][uP] = a1;
    red[(kq << 2) | 2][uP] = a2;
    red[(kq << 2) | 3][uP] = a3;
    __syncthreads();
    if (isP2) {
      const v4f gv = red[bD][uD] + red[4 + bD][uD] + red[8 + bD][uD] + red[12 + bD][uD];
      const float iv = sigm(gv.x + dbi2), fv = sigm(gv.y + dbf2);
      const float gva = tanhf(gv.z + dbg2), ov = sigm(gv.w + dbo2);
      cD = fv * cD + iv * gva;
      const float hn = ov * tanhf(cD);
      hsF[p ^ 1][(bD << 8) | uD] = hn;
      atomicExch(&hxMe[(bD << 7) | uL], pk(0xA5000000u, __float_as_uint(hn)));
      const unsigned pw = spinrd(&hxYo[(bD << 7) | uL], 0xA5000000u);
      hsF[p ^ 1][(bD << 8) | pbase | uL] = __uint_as_float(pw);
    }
    __syncthreads();
    p ^= 1;                                   // hsF[p] = full h_0
  }

#define WINNER(B, WI) { float _wv = oVs[B]; int _wi = oIs[B];                 \
    const float _ev = eVs[B]; const int _ei = eIs[B];                         \
    if (_ev > _wv || (_ev == _wv && _ei < _wi)) { _wi = _ei; }                \
    WI = _wi; }

  for (int t = 0; t < 256; ++t) {
    const unsigned tagA = 0xA5000001u + 2u * (unsigned)t;
    const unsigned tagH = 0xA5000002u + 2u * (unsigned)t;
    const v4f* hq = (const v4f*)&hsF[p][0];

    // ==== phase X: waves 0-7 Wh·h_t (u-half) ∥ waves 8-15 attention(t) ====
    if (wave < 8) {
      v4f a0 = (v4f)0.f, a1 = (v4f)0.f, a2 = (v4f)0.f, a3 = (v4f)0.f;
      const v4f* Wh = decWh4 + uPD;
#pragma unroll 2
      for (int kk = 0; kk < 16; ++kk) {
        const int k4 = k4bD + kk;
        const v4f w0 = Wh[(k4 * 4 + 0) << 8];
        const v4f w1 = Wh[(k4 * 4 + 1) << 8];
        const v4f w2 = Wh[(k4 * 4 + 2) << 8];
        const v4f w3 = Wh[(k4 * 4 + 3) << 8];
        const v4f h0 = hq[k4];
        const v4f h1 = hq[64 + k4];
        const v4f h2 = hq[128 + k4];
        const v4f h3 = hq[192 + k4];
        a0 += w0 * h0.x + w1 * h0.y + w2 * h0.z + w3 * h0.w;
        a1 += w0 * h1.x + w1 * h1.y + w2 * h1.z + w3 * h1.w;
        a2 += w0 * h2.x + w1 * h2.y + w2 * h2.z + w3 * h2.w;
        a3 += w0 * h3.x + w1 * h3.y + w2 * h3.z + w3 * h3.w;
      }
      red[(kqD << 2) | 0][uPD] = a0;
      red[(kqD << 2) | 1][uPD] = a1;
      red[(kqD << 2) | 2][uPD] = a2;
      red[(kqD << 2) | 3][uPD] = a3;
    } else {
      const int masked = maskC[bAt][sL];
      float sc = 0.f;
      if (!masked) {
        const v4f* E = encK4 + (bGt << 14) + sG;
        const v4f* hq2 = hq + (bAt << 6);
#pragma unroll 4
        for (int k4 = 0; k4 < 64; ++k4) {
          const v4f ev = E[k4 << 8];
          const v4f hv = hq2[k4];
          sc += ev.x * hv.x + ev.y * hv.y + ev.z * hv.z + ev.w * hv.w;
        }
      }
      unsigned bits;
      {
        unsigned kk0 = 0u, kk1 = (unsigned)t;
        tf2(0u, 42u, kk0, kk1);
        unsigned y0 = 0u, y1 = (unsigned)((bGt << 8) + sG);
        tf2(kk0, kk1, y0, y1);
        bits = y0 ^ y1;
      }
      const float fr = __uint_as_float((bits >> 9) | 0x3f800000u) - 1.0f;
      const float uu = (fr > 0.f) ? fr : 1.17549435e-38f;
      const float gum = -logf(-logf(uu));
      float bv = masked ? NEG_INF : (sc + gum);
      int bi = sG;
#pragma unroll
      for (int off = 32; off; off >>= 1) {
        const float ov2 = __shfl_xor(bv, off, 64);
        const int oi2 = __shfl_xor(bi, off, 64);
        if (ov2 > bv || (ov2 == bv && oi2 < bi)) { bv = ov2; bi = oi2; }
      }
      if (l == 0) { partV[bAt][aw & 1] = bv; partI[bAt][aw & 1] = bi; }
    }
    __syncthreads();                          // S1: red-Wh + partials ready

    // ==== local combine + publish (tid 0-3); spin partner (tid 64-71) ====
    if (tid < 4) {
      float v0 = partV[tid][0]; int i0 = partI[tid][0];
      const float v1 = partV[tid][1];
      if (v1 > v0) { v0 = v1; i0 = partI[tid][1]; }   // strict >: lower s kept
      oVs[tid] = v0; oIs[tid] = i0;
      atomicExch(&amxMe[tid * 2 + 0], pk(tagA, __float_as_uint(v0)));
      atomicExch(&amxMe[tid * 2 + 1], pk(tagA, (unsigned)i0));
    }
    if (tid >= 64 && tid < 72) {
      const int j = tid - 64;                 // b*2 + {val,idx}
      const unsigned pw = spinrd(&amxYo[j], tagA);
      if (j & 1) eIs[j >> 1] = (int)pw;
      else       eVs[j >> 1] = __uint_as_float(pw);
    }
    __syncthreads();                          // S2: both halves' results ready

    // ==== winner, mask, out, din staging ====
    if (wave >= 8) {
      int wi; WINNER(bAt, wi);
      if (sG == wi) maskC[bAt][sL] = 1;
    }
    if (H == 0 && tid < 4) {
      int wi; WINNER(tid, wi);
      out[((b0 + tid) << 8) + t] = wi;
    }
    if (tid < 256) {
      const int bb = tid >> 6, k4s = tid & 63;
      int wi; WINNER(bb, wi);
      dinV[tid] = encK4[((((b0 + bb) << 6) | k4s) << 8) + wi];
    }
    __syncthreads();                          // S3: din/mask ready

    if (t == 255) break;                      // last index emitted

    // ==== Wi·din sweep (waves 0-7, continue chain from red — lossless) ====
    if (wave < 8) {
      v4f a0 = red[(kqD << 2) | 0][uPD];
      v4f a1 = red[(kqD << 2) | 1][uPD];
      v4f a2 = red[(kqD << 2) | 2][uPD];
      v4f a3 = red[(kqD << 2) | 3][uPD];
      const v4f* Wi = decWi4 + uPD;
#pragma unroll 2
      for (int kk = 0; kk < 16; ++kk) {
        const int k4 = k4bD + kk;
        const v4f w0 = Wi[(k4 * 4 + 0) << 8];
        const v4f w1 = Wi[(k4 * 4 + 1) << 8];
        const v4f w2 = Wi[(k4 * 4 + 2) << 8];
        const v4f w3 = Wi[(k4 * 4 + 3) << 8];
        const v4f d0 = dinV[k4];
        const v4f d1 = dinV[64 + k4];
        const v4f d2 = dinV[128 + k4];
        const v4f d3 = dinV[192 + k4];
        a0 += w0 * d0.x + w1 * d0.y + w2 * d0.z + w3 * d0.w;
        a1 += w0 * d1.x + w1 * d1.y + w2 * d1.z + w3 * d1.w;
        a2 += w0 * d2.x + w1 * d2.y + w2 * d2.z + w3 * d2.w;
        a3 += w0 * d3.x + w1 * d3.y + w2 * d3.z + w3 * d3.w;
      }
      red[(kqD << 2) | 0][uPD] = a0;
      red[(kqD << 2) | 1][uPD] = a1;
      red[(kqD << 2) | 2][uPD] = a2;
      red[(kqD << 2) | 3][uPD] = a3;
    }
    __syncthreads();                          // S4: full partials ready

    // ==== P2 (split) -> h_{t+1}; publish + fetch partner half ====
    if (isP2) {
      const v4f gv = red[bD][uD] + red[4 + bD][uD] + red[8 + bD][uD] + red[12 + bD][uD];
      const float iv = sigm(gv.x + dbi2), fv = sigm(gv.y + dbf2);
      const float gva = tanhf(gv.z + dbg2), ov = sigm(gv.w + dbo2);
      cD = fv * cD + iv * gva;
      const float hn = ov * tanhf(cD);
      hsF[p ^ 1][(bD << 8) | uD] = hn;
      atomicExch(&hxMe[(bD << 7) | uL], pk(tagH, __float_as_uint(hn)));
      const unsigned pw = spinrd(&hxYo[(bD << 7) | uL], tagH);
      hsF[p ^ 1][(bD << 8) | pbase | uL] = __uint_as_float(pw);
    }
    __syncthreads();                          // S5: full h_{t+1} ready
    p ^= 1;
  }
#undef WINNER
}

extern "C" void kernel_launch(void* const* d_in, const int* in_sizes, int n_in,
                              void* d_out, int out_size, void* d_ws, size_t ws_size,
                              hipStream_t stream) {
  (void)in_sizes; (void)n_in; (void)out_size;
  if (ws_size < WS_NEEDED) return;   // need ~139 MB scratch

  const float* inp = (const float*)d_in[0];
  const float* eWi = (const float*)d_in[1];
  const float* eWh = (const float*)d_in[2];
  const float* eBi = (const float*)d_in[3];
  const float* eBh = (const float*)d_in[4];
  const float* dWi = (const float*)d_in[5];
  const float* dWh = (const float*)d_in[6];
  const float* dBi = (const float*)d_in[7];
  const float* dBh = (const float*)d_in[8];
  int* out = (int*)d_out;
  float* wsf = (float*)d_ws;

  // zero the sync region every launch: fresh tags, no ABA across graph replays
  hipMemsetAsync((char*)d_ws + WS_HX_OFF, 0, WS_SYNC_BYTES, stream);
  hipLaunchKernelGGL(repack_k, dim3(256), dim3(256), 0, stream, eWh, dWi, dWh, wsf);
  hipLaunchKernelGGL(ptrnet_kernel, dim3(256), dim3(1024), 0, stream,
                     inp, eWi, eBi, eBh, dBi, dBh, out, wsf);
}